// Round 1
// baseline (2306.234 us; speedup 1.0000x reference)
//
#include <hip/hip_runtime.h>
#include <math.h>

#define B 8
#define N 4096
#define C 512
#define K 130
#define KP 144                    // K padded to 16 groups * 9 for LDS tiles
#define BNK (B*N*K)               // 4,259,840 floats per stream
#define BCK (B*C*K)               // 532,480 floats per stream
#define BK  (B*K)                 // 1040

// ---------------- adaptive max pool over last dim: (b,n,C) -> (b,n,K) ----------------
__global__ __launch_bounds__(256) void pool_kernel(const float* __restrict__ x1,
        const float* __restrict__ x2, float* __restrict__ out)
{
    const float* x = blockIdx.y ? x2 : x1;
    float* o = out + (size_t)blockIdx.y * BNK;
    int idx = blockIdx.x * 256 + threadIdx.x;
    if (idx >= BNK) return;
    int kk = idx % K;
    int bn = idx / K;
    int start = (kk * C) / K;
    int end = ((kk + 1) * C + K - 1) / K;   // ceil
    const float* row = x + (size_t)bn * C;
    float m = row[start];
    for (int c = start + 1; c < end; ++c) m = fmaxf(m, row[c]);
    o[idx] = m;
}

// ---- column sum-of-squares over rows (axis with stride K); atomic partials ----
// v laid out (b, rows, K); rows = nch*128 per b.  sums[s*BK + b*K + kk] += sum v^2
__global__ __launch_bounds__(256) void colsq_kernel(const float* __restrict__ v,
        float* __restrict__ sums, int nch, size_t sStride)
{
    int s = blockIdx.y;
    int b = blockIdx.x / nch;
    int ch = blockIdx.x % nch;
    __shared__ float sh[K];
    if (threadIdx.x < K) sh[threadIdx.x] = 0.f;
    __syncthreads();
    const float* base = v + s * sStride + (size_t)((b * nch + ch) * 128) * K;
    for (int flat = threadIdx.x; flat < 128 * K; flat += 256) {
        float val = base[flat];
        atomicAdd(&sh[flat % K], val * val);
    }
    __syncthreads();
    if (threadIdx.x < K) atomicAdd(&sums[s * BK + b * K + threadIdx.x], sh[threadIdx.x]);
}

// ---------------- GEMM1: z[b,c,kk] = sum_n x[b,n,c] * (kin[b,n,kk] * inv_norm_k[b,kk]) ----------------
#define G1_NSTEP 16
#define G1_NCHUNKS 4
#define G1_NCH (N / G1_NCHUNKS)   // 1024
__global__ __launch_bounds__(256) void gemm1_kernel(const float* __restrict__ x1,
        const float* __restrict__ x2, const float* __restrict__ kq,
        const float* __restrict__ nk, float* __restrict__ z)
{
    int s = blockIdx.y;
    const float* x = s ? x2 : x1;
    const float* kin = kq + (size_t)s * BNK;
    const float* sums = nk + s * BK;
    float* zout = z + (size_t)s * BCK;

    int bid = blockIdx.x;                    // B * 8 * G1_NCHUNKS
    int nch = bid & (G1_NCHUNKS - 1);
    int ct  = (bid / G1_NCHUNKS) & 7;
    int b   = bid / (G1_NCHUNKS * 8);
    int c0 = ct * 64;
    int n0 = nch * G1_NCH;

    __shared__ __align__(16) float xs[G1_NSTEP][64];
    __shared__ __align__(16) float ks[G1_NSTEP][KP];

    int t = threadIdx.x;
    int cg = t & 15;                 // 16 c-subgroups * 4 c each = 64
    int g  = t >> 4;                 // 16 kk-groups * 9 kk each = 144 (pad)
    int kk0 = g * 9;

    float acc[4][9];
    #pragma unroll
    for (int e = 0; e < 4; ++e)
        #pragma unroll
        for (int j = 0; j < 9; ++j) acc[e][j] = 0.f;

    for (int nb = n0; nb < n0 + G1_NCH; nb += G1_NSTEP) {
        #pragma unroll
        for (int r = 0; r < 4; ++r) {                   // x tile: 16 n x 64 c, coalesced
            int flat = t + r * 256;
            int i = flat >> 6, col = flat & 63;
            xs[i][col] = x[(size_t)(b * N + nb + i) * C + c0 + col];
        }
        const float* ksrc = kin + (size_t)(b * N + nb) * K;  // k tile: 16 n x K (zero-pad to KP)
        for (int flat = t; flat < G1_NSTEP * KP; flat += 256) {
            int i = flat / KP, kk = flat % KP;
            ks[i][kk] = (kk < K) ? ksrc[i * K + kk] : 0.f;
        }
        __syncthreads();
        for (int i = 0; i < G1_NSTEP; ++i) {
            float4 xv4 = *reinterpret_cast<const float4*>(&xs[i][cg * 4]);
            float xv[4] = {xv4.x, xv4.y, xv4.z, xv4.w};
            float kv[9];
            #pragma unroll
            for (int j = 0; j < 9; ++j) kv[j] = ks[i][kk0 + j];
            #pragma unroll
            for (int e = 0; e < 4; ++e)
                #pragma unroll
                for (int j = 0; j < 9; ++j)
                    acc[e][j] = fmaf(xv[e], kv[j], acc[e][j]);
        }
        __syncthreads();
    }
    #pragma unroll
    for (int j = 0; j < 9; ++j) {
        int kk = kk0 + j;
        if (kk < K) {
            float inv = 1.f / (1e-6f + sqrtf(sums[b * K + kk]));
            #pragma unroll
            for (int e = 0; e < 4; ++e) {
                int c = c0 + cg * 4 + e;
                atomicAdd(&zout[(size_t)(b * C + c) * K + kk], acc[e][j] * inv);
            }
        }
    }
}

// ---------------- softmax over kk (rows of length K, contiguous); one wave per row ----------------
__global__ __launch_bounds__(256) void softmax_kernel(float* __restrict__ z)
{
    float* zb = z + (size_t)blockIdx.y * BCK;
    int wave = threadIdx.x >> 6;
    int lane = threadIdx.x & 63;
    int row = blockIdx.x * 4 + wave;            // 0 .. B*C-1
    float* r = zb + (size_t)row * K;
    float v0 = r[lane];
    float v1 = r[lane + 64];
    float v2 = (lane < 2) ? r[128 + lane] : -3.4e38f;
    float m = fmaxf(fmaxf(v0, v1), v2);
    #pragma unroll
    for (int off = 32; off; off >>= 1) m = fmaxf(m, __shfl_xor(m, off, 64));
    float e0 = expf(v0 - m), e1 = expf(v1 - m);
    float e2 = (lane < 2) ? expf(v2 - m) : 0.f;
    float sum = e0 + e1 + e2;
    #pragma unroll
    for (int off = 32; off; off >>= 1) sum += __shfl_xor(sum, off, 64);
    float inv = 1.f / sum;
    r[lane] = e0 * inv;
    r[lane + 64] = e1 * inv;
    if (lane < 2) r[128 + lane] = e2 * inv;
}

// ---------------- GEMM2: kout[b,n,kk] = sum_c x[b,n,c] * (z[b,c,kk] * inv_norm_z[b,kk]) ----------------
#define G2_CSTEP 16
__global__ __launch_bounds__(256) void gemm2_kernel(const float* __restrict__ x1,
        const float* __restrict__ x2, const float* __restrict__ z,
        const float* __restrict__ nz, float* __restrict__ kq)
{
    int s = blockIdx.y;
    const float* x = s ? x2 : x1;
    const float* zb = z + (size_t)s * BCK;
    const float* sums = nz + s * BK;
    float* kout = kq + (size_t)s * BNK;

    int bid = blockIdx.x;            // B * 64
    int nt = bid & 63;
    int b  = bid >> 6;
    int n0 = nt * 64;

    __shared__ __align__(16) float xs[G2_CSTEP][68];   // [c][n], pad 64->68 keeps 16B row align, no bank conflict
    __shared__ __align__(16) float ks[G2_CSTEP][KP];

    int t = threadIdx.x;
    int ng = t & 15;                 // 16 n-subgroups * 4 n each = 64
    int g  = t >> 4;
    int kk0 = g * 9;

    float acc[4][9];
    #pragma unroll
    for (int e = 0; e < 4; ++e)
        #pragma unroll
        for (int j = 0; j < 9; ++j) acc[e][j] = 0.f;

    for (int cb = 0; cb < C; cb += G2_CSTEP) {
        #pragma unroll
        for (int r = 0; r < 4; ++r) {                   // x tile 64 n x 16 c, stored transposed [c][n]
            int flat = t + r * 256;
            int row = flat >> 4, col = flat & 15;
            xs[col][row] = x[(size_t)(b * N + n0 + row) * C + cb + col];
        }
        const float* zsrc = zb + (size_t)(b * C + cb) * K;
        for (int flat = t; flat < G2_CSTEP * KP; flat += 256) {
            int i = flat / KP, kk = flat % KP;
            ks[i][kk] = (kk < K) ? zsrc[i * K + kk] : 0.f;
        }
        __syncthreads();
        for (int i = 0; i < G2_CSTEP; ++i) {
            float4 xv4 = *reinterpret_cast<const float4*>(&xs[i][ng * 4]);
            float xv[4] = {xv4.x, xv4.y, xv4.z, xv4.w};
            float kv[9];
            #pragma unroll
            for (int j = 0; j < 9; ++j) kv[j] = ks[i][kk0 + j];
            #pragma unroll
            for (int e = 0; e < 4; ++e)
                #pragma unroll
                for (int j = 0; j < 9; ++j)
                    acc[e][j] = fmaf(xv[e], kv[j], acc[e][j]);
        }
        __syncthreads();
    }
    #pragma unroll
    for (int j = 0; j < 9; ++j) {
        int kk = kk0 + j;
        if (kk < K) {
            float inv = 1.f / (1e-6f + sqrtf(sums[b * K + kk]));
            #pragma unroll
            for (int e = 0; e < 4; ++e) {
                int n = n0 + ng * 4 + e;
                kout[(size_t)(b * N + n) * K + kk] = acc[e][j] * inv;
            }
        }
    }
}

// ---------------- final l2norm materialization: out *= 1/(1e-6+sqrt(colsq)) ----------------
__global__ __launch_bounds__(256) void scale_kernel(float* __restrict__ out,
        const float* __restrict__ nk)
{
    int s = blockIdx.y;
    int idx = blockIdx.x * 256 + threadIdx.x;
    if (idx >= BNK) return;
    int kk = idx % K;
    int b = idx / (N * K);
    out[(size_t)s * BNK + idx] *= 1.f / (1e-6f + sqrtf(nk[s * BK + b * K + kk]));
}

extern "C" void kernel_launch(void* const* d_in, const int* in_sizes, int n_in,
                              void* d_out, int out_size, void* d_ws, size_t ws_size,
                              hipStream_t stream)
{
    (void)in_sizes; (void)n_in; (void)out_size; (void)ws_size;
    const float* x1 = (const float*)d_in[0];
    const float* x2 = (const float*)d_in[1];
    float* out = (float*)d_out;               // [k (BNK) | q (BNK)], unnormalized until final scale
    float* z  = (float*)d_ws;                 // 2*BCK
    float* nk = z + 2 * BCK;                  // 2*BK  (colsq of k/q over n)
    float* nz = nk + 2 * BK;                  // 2*BK  (colsq of z over c)

    dim3 blk(256);
    pool_kernel<<<dim3((BNK + 255) / 256, 2), blk, 0, stream>>>(x1, x2, out);
    hipMemsetAsync(nk, 0, sizeof(float) * 2 * BK, stream);
    colsq_kernel<<<dim3(B * 32, 2), blk, 0, stream>>>(out, nk, 32, (size_t)BNK);

    for (int st = 0; st < 3; ++st) {
        hipMemsetAsync(z, 0, sizeof(float) * 2 * BCK, stream);
        gemm1_kernel<<<dim3(B * 8 * G1_NCHUNKS, 2), blk, 0, stream>>>(x1, x2, out, nk, z);
        softmax_kernel<<<dim3(B * C / 4, 2), blk, 0, stream>>>(z);
        hipMemsetAsync(nz, 0, sizeof(float) * 2 * BK, stream);
        colsq_kernel<<<dim3(B * 4, 2), blk, 0, stream>>>(z, nz, 4, (size_t)BCK);
        gemm2_kernel<<<dim3(B * 64, 2), blk, 0, stream>>>(x1, x2, z, nz, out);
        hipMemsetAsync(nk, 0, sizeof(float) * 2 * BK, stream);
        colsq_kernel<<<dim3(B * 32, 2), blk, 0, stream>>>(out, nk, 32, (size_t)BNK);
    }
    scale_kernel<<<dim3((BNK + 255) / 256, 2), blk, 0, stream>>>(out, nk);
}

// Round 5
// 1155.180 us; speedup vs baseline: 1.9964x; 1.9964x over previous
//
#include <hip/hip_runtime.h>
#include <math.h>
#include <float.h>

#define B 8
#define N 4096
#define C 512
#define K 130
#define KP 144
#define BNK (B*N*K)
#define SB(s,b) ((s)*B + (b))

typedef __bf16 bf16x8 __attribute__((ext_vector_type(8)));
typedef __bf16 bf16x4 __attribute__((ext_vector_type(4)));
typedef float  f32x4  __attribute__((ext_vector_type(4)));

// ws layout (bytes); total ~85 MB (proven-safe: R1 ran at 160 MB)
#define SZ_KQ   18874368ull                 // bf16 [2][B][KP][N]
#define SLAB    1179648ull                  // floats per zpart slab: 16*KP*C
#define OFS_KQH 0ull
#define OFS_KQL (OFS_KQH + SZ_KQ)
#define OFS_ZP  (OFS_KQL + SZ_KQ)           // float [8][16][KP][C] partials
#define OFS_ZT  (OFS_ZP + 8ull*SLAB*4ull)   // float [16][KP][C]
#define OFS_ZH  (OFS_ZT + SLAB*4ull)        // bf16
#define OFS_ZL  (OFS_ZH + SLAB*2ull)
#define OFS_NKI (OFS_ZL + SLAB*2ull)
#define OFS_NZI (OFS_NKI + 9216ull)

__device__ __forceinline__ void split2(float v, __bf16& h, __bf16& l) {
    h = (__bf16)v;
    l = (__bf16)(v - (float)h);
}
// split into ext-vector elements (can't bind refs to vector elements)
#define SPLIT_VEC(v, vh, vl, i) { __bf16 _h = (__bf16)(v); (vh)[i] = _h; (vl)[i] = (__bf16)((v) - (float)_h); }

// ---------- adaptive max pool from fp32 x -> kq hi/lo [s][b][kk][n] ----------
__global__ __launch_bounds__(256) void pool_kernel(const float* __restrict__ x1,
        const float* __restrict__ x2, __bf16* __restrict__ kqh, __bf16* __restrict__ kql)
{
    int s = blockIdx.y;
    const float* x = s ? x2 : x1;
    int bx = blockIdx.x;                 // nch(256) * b(8)
    int nch = bx & 255, b = bx >> 8;
    int n0 = nch * 16;
    __shared__ float tile[16 * 516];
    int t = threadIdx.x;
    #pragma unroll
    for (int it = 0; it < 8; ++it) {     // 16 rows x 128 float4
        int flat = it * 256 + t;
        int row = flat >> 7, c4 = flat & 127;
        float4 v = *(const float4*)(x + (size_t)(b * N + n0 + row) * C + c4 * 4);
        *(float4*)(&tile[row * 516 + c4 * 4]) = v;
    }
    __syncthreads();
    int n = t & 15, kgrp = t >> 4;
    #pragma unroll
    for (int j = 0; j < 9; ++j) {
        int kk = kgrp + 16 * j;          // covers 0..143
        size_t doff = ((size_t)(SB(s,b) * KP + kk)) * N + n0 + n;
        if (kk >= K) { kqh[doff] = (__bf16)0.f; kql[doff] = (__bf16)0.f; continue; }
        int start = (kk * C) / K;
        int end = ((kk + 1) * C + K - 1) / K;
        float m = tile[n * 516 + start];
        for (int c = start + 1; c < end; ++c) m = fmaxf(m, tile[n * 516 + c]);
        __bf16 h, l; split2(m, h, l);
        kqh[doff] = h; kql[doff] = l;
    }
}

// ---------- row l2-norm reciprocal of kq rows (length N, hi+lo) ----------
__global__ __launch_bounds__(256) void knorm_kernel(const __bf16* __restrict__ kqh,
        const __bf16* __restrict__ kql, float* __restrict__ nkinv)
{
    int s = blockIdx.y;
    int w = threadIdx.x >> 6, l = threadIdx.x & 63;
    int r = blockIdx.x * 4 + w;          // < B*KP
    int kk = r % KP, b = r / KP;
    size_t base = ((size_t)(SB(s,b) * KP + kk)) * N;
    const bf16x8* ph = (const bf16x8*)(kqh + base);
    const bf16x8* pl = (const bf16x8*)(kql + base);
    float sum = 0.f;
    #pragma unroll
    for (int i = 0; i < 8; ++i) {
        bf16x8 vh = ph[l + i * 64], vl = pl[l + i * 64];
        #pragma unroll
        for (int j = 0; j < 8; ++j) { float f = (float)vh[j] + (float)vl[j]; sum = fmaf(f, f, sum); }
    }
    #pragma unroll
    for (int off = 32; off; off >>= 1) sum += __shfl_xor(sum, off, 64);
    if (l == 0) nkinv[SB(s,b) * KP + kk] = 1.f / (1e-6f + sqrtf(sum));
}

// ---------- GEMM1 (split): zpart[p][kk][c] = sum_n kq[kk][n]*x[n][c] * nkinv[kk] ----------
__global__ __launch_bounds__(256, 2) void gemm1_kernel(const float* __restrict__ x1,
        const float* __restrict__ x2, const __bf16* __restrict__ kqh,
        const __bf16* __restrict__ kql, const float* __restrict__ nkinv,
        float* __restrict__ zpart)
{
    int s = blockIdx.y;
    const float* x = s ? x2 : x1;
    int bx = blockIdx.x;                 // cs(4) * b(8) * nsp(8)
    int cs = bx & 3, b = (bx >> 2) & 7, nsp = bx >> 5;
    int sb = SB(s,b);
    int c0 = cs * 128, n0 = nsp * 512;
    int t = threadIdx.x, w = t >> 6, l = t & 63, quad = l >> 4, lm = l & 15;

    __shared__ __bf16 ldsh[128 * 40];
    __shared__ __bf16 ldsl[128 * 40];

    f32x4 acc[9][2];
    #pragma unroll
    for (int kkt = 0; kkt < 9; ++kkt)
        #pragma unroll
        for (int ct = 0; ct < 2; ++ct) { acc[kkt][ct][0]=0.f; acc[kkt][ct][1]=0.f; acc[kkt][ct][2]=0.f; acc[kkt][ct][3]=0.f; }

    int cload = t & 127;                 // staging c
    int ngrp = t >> 7;                   // staging n group (0/1)
    size_t kqbase = (size_t)(sb * KP) * N;

    for (int step = 0; step < 16; ++step) {
        int nb = n0 + step * 32;
        __syncthreads();
        #pragma unroll
        for (int p = 0; p < 4; ++p) {    // stage x[nb..nb+32][c0..c0+128] -> lds [c][n] hi/lo
            int nl = ngrp * 16 + p * 4;
            const float* xp = x + (size_t)(b * N + nb + nl) * C + c0 + cload;
            float v0 = xp[0], v1 = xp[C], v2 = xp[2*C], v3 = xp[3*C];
            bf16x4 vh, vl;
            SPLIT_VEC(v0, vh, vl, 0); SPLIT_VEC(v1, vh, vl, 1);
            SPLIT_VEC(v2, vh, vl, 2); SPLIT_VEC(v3, vh, vl, 3);
            *(bf16x4*)(&ldsh[cload * 40 + nl]) = vh;
            *(bf16x4*)(&ldsl[cload * 40 + nl]) = vl;
        }
        __syncthreads();
        bf16x8 bh[2], bl[2];
        #pragma unroll
        for (int ct = 0; ct < 2; ++ct) {
            int cl = w * 32 + ct * 16 + lm;
            bh[ct] = *(const bf16x8*)(&ldsh[cl * 40 + quad * 8]);
            bl[ct] = *(const bf16x8*)(&ldsl[cl * 40 + quad * 8]);
        }
        #pragma unroll
        for (int kkt = 0; kkt < 9; ++kkt) {
            size_t ao = kqbase + (size_t)(kkt * 16 + lm) * N + nb + quad * 8;
            bf16x8 ah = *(const bf16x8*)(kqh + ao);
            bf16x8 al = *(const bf16x8*)(kql + ao);
            #pragma unroll
            for (int ct = 0; ct < 2; ++ct) {
                acc[kkt][ct] = __builtin_amdgcn_mfma_f32_16x16x32_bf16(ah, bh[ct], acc[kkt][ct], 0, 0, 0);
                acc[kkt][ct] = __builtin_amdgcn_mfma_f32_16x16x32_bf16(al, bh[ct], acc[kkt][ct], 0, 0, 0);
                acc[kkt][ct] = __builtin_amdgcn_mfma_f32_16x16x32_bf16(ah, bl[ct], acc[kkt][ct], 0, 0, 0);
            }
        }
    }
    float* zp = zpart + ((size_t)nsp * 16 + sb) * KP * C;
    #pragma unroll
    for (int kkt = 0; kkt < 9; ++kkt) {
        #pragma unroll
        for (int i = 0; i < 4; ++i) {
            int kk = kkt * 16 + quad * 4 + i;
            float inv = nkinv[sb * KP + kk];
            #pragma unroll
            for (int ct = 0; ct < 2; ++ct) {
                int c = c0 + w * 32 + ct * 16 + lm;
                zp[(size_t)kk * C + c] = acc[kkt][ct][i] * inv;
            }
        }
    }
}

// ---------- softmax over kk: sum 8 partials, softmax, write zT fp32 + zh/zl ----------
__global__ __launch_bounds__(256) void softmax_kernel(const float* __restrict__ zpart,
        float* __restrict__ zT, __bf16* __restrict__ zh, __bf16* __restrict__ zl)
{
    int s = blockIdx.y;
    int t = threadIdx.x;
    int colL = t >> 2, r = t & 3;
    int idx = blockIdx.x * 64 + colL;    // < B*C
    int b = idx >> 9, c = idx & 511;
    int sb = SB(s,b);
    size_t base0 = (size_t)sb * KP * C + c;
    float m = -FLT_MAX;
    for (int kk = r; kk < K; kk += 4) {
        float v = 0.f;
        #pragma unroll
        for (int p = 0; p < 8; ++p)
            v += zpart[((size_t)p * 16 + sb) * KP * C + (size_t)kk * C + c];
        zT[base0 + (size_t)kk * C] = v;
        m = fmaxf(m, v);
    }
    m = fmaxf(m, __shfl_xor(m, 1, 64));
    m = fmaxf(m, __shfl_xor(m, 2, 64));
    float sum = 0.f;
    for (int kk = r; kk < K; kk += 4) {
        float e = expf(zT[base0 + (size_t)kk * C] - m);
        zT[base0 + (size_t)kk * C] = e;
        sum += e;
    }
    sum += __shfl_xor(sum, 1, 64);
    sum += __shfl_xor(sum, 2, 64);
    float inv = 1.f / sum;
    for (int kk = r; kk < K; kk += 4) {
        float v = zT[base0 + (size_t)kk * C] * inv;
        zT[base0 + (size_t)kk * C] = v;
        __bf16 h, lo; split2(v, h, lo);
        zh[base0 + (size_t)kk * C] = h;
        zl[base0 + (size_t)kk * C] = lo;
    }
    for (int kk = K + r; kk < KP; kk += 4) {
        zT[base0 + (size_t)kk * C] = 0.f;
        zh[base0 + (size_t)kk * C] = (__bf16)0.f;
        zl[base0 + (size_t)kk * C] = (__bf16)0.f;
    }
}

// ---------- row l2-norm reciprocal of zT rows (length C, fp32) ----------
__global__ __launch_bounds__(256) void znorm_kernel(const float* __restrict__ zT,
        float* __restrict__ nzinv)
{
    int s = blockIdx.y;
    int w = threadIdx.x >> 6, l = threadIdx.x & 63;
    int r = blockIdx.x * 4 + w;
    int kk = r % KP, b = r / KP;
    const float4* p = (const float4*)(zT + ((size_t)(SB(s,b) * KP + kk)) * C);
    float sum = 0.f;
    #pragma unroll
    for (int i = 0; i < 2; ++i) {
        float4 v = p[l + i * 64];
        sum = fmaf(v.x, v.x, sum); sum = fmaf(v.y, v.y, sum);
        sum = fmaf(v.z, v.z, sum); sum = fmaf(v.w, v.w, sum);
    }
    #pragma unroll
    for (int off = 32; off; off >>= 1) sum += __shfl_xor(sum, off, 64);
    if (l == 0) nzinv[SB(s,b) * KP + kk] = 1.f / (1e-6f + sqrtf(sum));
}

// ---------- GEMM2 (split): out[n][kk] = sum_c x[n][c]*z[kk][c] * nzinv[kk] ----------
__global__ __launch_bounds__(256, 2) void gemm2_kernel(const float* __restrict__ x1,
        const float* __restrict__ x2, const __bf16* __restrict__ zh,
        const __bf16* __restrict__ zl, const float* __restrict__ nzinv,
        float* __restrict__ out, __bf16* __restrict__ kqh, __bf16* __restrict__ kql)
{
    int s = blockIdx.y;
    const float* x = s ? x2 : x1;
    int bx = blockIdx.x;                 // nt(64) * b(8)
    int nt = bx & 63, b = bx >> 6, sb = SB(s,b);
    int t = threadIdx.x, w = t >> 6, l = t & 63, quad = l >> 4, lm = l & 15;
    const float* Abase = x + (size_t)(b * N + nt * 64 + w * 16 + lm) * C;
    size_t Boff = (size_t)(sb * KP) * C;
    f32x4 acc[9];
    #pragma unroll
    for (int kkt = 0; kkt < 9; ++kkt) { acc[kkt][0]=0.f; acc[kkt][1]=0.f; acc[kkt][2]=0.f; acc[kkt][3]=0.f; }
    for (int cb = 0; cb < C; cb += 32) {
        float4 u = *(const float4*)(Abase + cb + quad * 8);
        float4 v = *(const float4*)(Abase + cb + quad * 8 + 4);
        bf16x8 ah, al;
        SPLIT_VEC(u.x, ah, al, 0); SPLIT_VEC(u.y, ah, al, 1);
        SPLIT_VEC(u.z, ah, al, 2); SPLIT_VEC(u.w, ah, al, 3);
        SPLIT_VEC(v.x, ah, al, 4); SPLIT_VEC(v.y, ah, al, 5);
        SPLIT_VEC(v.z, ah, al, 6); SPLIT_VEC(v.w, ah, al, 7);
        #pragma unroll
        for (int kkt = 0; kkt < 9; ++kkt) {
            size_t bo = Boff + (size_t)(kkt * 16 + lm) * C + cb + quad * 8;
            bf16x8 bh = *(const bf16x8*)(zh + bo);
            bf16x8 bl = *(const bf16x8*)(zl + bo);
            acc[kkt] = __builtin_amdgcn_mfma_f32_16x16x32_bf16(ah, bh, acc[kkt], 0, 0, 0);
            acc[kkt] = __builtin_amdgcn_mfma_f32_16x16x32_bf16(al, bh, acc[kkt], 0, 0, 0);
            acc[kkt] = __builtin_amdgcn_mfma_f32_16x16x32_bf16(ah, bl, acc[kkt], 0, 0, 0);
        }
    }
    __shared__ __bf16 ldsh[KP * 68];
    __shared__ __bf16 ldsl[KP * 68];
    #pragma unroll
    for (int kkt = 0; kkt < 9; ++kkt) {
        int kk = kkt * 16 + lm;
        float inv = nzinv[sb * KP + kk];
        bf16x4 v4h, v4l;
        #pragma unroll
        for (int i = 0; i < 4; ++i) {
            int n = nt * 64 + w * 16 + quad * 4 + i;
            float val = acc[kkt][i] * inv;
            if (kk < K) out[(size_t)s * BNK + (size_t)(b * N + n) * K + kk] = val;
            SPLIT_VEC(val, v4h, v4l, i);
        }
        *(bf16x4*)(&ldsh[kk * 68 + w * 16 + quad * 4]) = v4h;
        *(bf16x4*)(&ldsl[kk * 68 + w * 16 + quad * 4]) = v4l;
    }
    __syncthreads();
    #pragma unroll
    for (int it = 0; it < 36; ++it) {    // KP*64
        int flat = it * 256 + t;
        int kk = flat >> 6, nl = flat & 63;
        size_t o = ((size_t)(sb * KP + kk)) * N + nt * 64 + nl;
        kqh[o] = ldsh[kk * 68 + nl];
        kql[o] = ldsl[kk * 68 + nl];
    }
}

// ---------- final: out *= nkinv ----------
__global__ __launch_bounds__(256) void scale_kernel(float* __restrict__ out,
        const float* __restrict__ nkinv)
{
    int s = blockIdx.y;
    int idx = blockIdx.x * 256 + threadIdx.x;
    if (idx >= BNK) return;
    int kk = idx % K;
    int b = idx / (N * K);
    out[(size_t)s * BNK + idx] *= nkinv[SB(s,b) * KP + kk];
}

extern "C" void kernel_launch(void* const* d_in, const int* in_sizes, int n_in,
                              void* d_out, int out_size, void* d_ws, size_t ws_size,
                              hipStream_t stream)
{
    (void)in_sizes; (void)n_in; (void)out_size; (void)ws_size;
    const float* x1 = (const float*)d_in[0];
    const float* x2 = (const float*)d_in[1];
    float* out = (float*)d_out;
    char* w = (char*)d_ws;
    __bf16* kqh = (__bf16*)(w + OFS_KQH);
    __bf16* kql = (__bf16*)(w + OFS_KQL);
    float*  zp  = (float*)(w + OFS_ZP);
    float*  zT  = (float*)(w + OFS_ZT);
    __bf16* zh  = (__bf16*)(w + OFS_ZH);
    __bf16* zl  = (__bf16*)(w + OFS_ZL);
    float*  nki = (float*)(w + OFS_NKI);
    float*  nzi = (float*)(w + OFS_NZI);

    dim3 blk(256);
    pool_kernel <<<dim3(256*B, 2), blk, 0, stream>>>(x1, x2, kqh, kql);
    knorm_kernel<<<dim3(B*KP/4, 2), blk, 0, stream>>>(kqh, kql, nki);

    for (int st = 0; st < 3; ++st) {
        gemm1_kernel  <<<dim3(256, 2), blk, 0, stream>>>(x1, x2, kqh, kql, nki, zp);
        softmax_kernel<<<dim3(B*C/64, 2), blk, 0, stream>>>(zp, zT, zh, zl);
        znorm_kernel  <<<dim3(B*KP/4, 2), blk, 0, stream>>>(zT, nzi);
        gemm2_kernel  <<<dim3(64*B, 2), blk, 0, stream>>>(x1, x2, zh, zl, nzi, out, kqh, kql);
        knorm_kernel  <<<dim3(B*KP/4, 2), blk, 0, stream>>>(kqh, kql, nki);
    }
    scale_kernel    <<<dim3((BNK+255)/256, 2), blk, 0, stream>>>(out, nki);
}